// Round 19
// baseline (168.851 us; speedup 1.0000x reference)
//
#include <hip/hip_runtime.h>
#include <hip/hip_bf16.h>
#include <stdint.h>

#define D_MODEL 768
#define NHEADS 12
#define HD 64
#define SEQ 4096
#define BATCH 2
#define MTOT (BATCH*SEQ)        // 8192
#define BHN (BATCH*NHEADS)      // 24

typedef __attribute__((ext_vector_type(8))) short short8;
typedef __attribute__((ext_vector_type(4))) float f32x4;
typedef __attribute__((ext_vector_type(16))) float f32x16;
typedef __attribute__((ext_vector_type(4))) int i32x4;

__device__ inline unsigned short f2bf(float f) {
  union { float f; unsigned u; } v; v.f = f;
  unsigned r = (v.u + 0x7FFFu + ((v.u >> 16) & 1u)) >> 16;
  return (unsigned short)r;
}
__device__ inline unsigned cvtpk_bf16(float lo, float hi) {
  unsigned r;
  asm("v_cvt_pk_bf16_f32 %0, %1, %2" : "=v"(r) : "v"(lo), "v"(hi));
  return r;
}
__device__ inline void perm32swap(unsigned &a, unsigned &b) {
  asm("v_permlane32_swap_b32 %0, %1" : "+v"(a), "+v"(b));
}
__device__ inline float exp2fast(float x) {   // v_exp_f32: D = 2^S0
  float r;
  asm("v_exp_f32 %0, %1" : "=v"(r) : "v"(x));
  return r;
}
// async global->LDS, 16B per lane. lds dest = wave-uniform base + lane*16.
__device__ inline void gload16(const void* g, void* l) {
  __builtin_amdgcn_global_load_lds(
      (const __attribute__((address_space(1))) unsigned int*)g,
      (__attribute__((address_space(3))) unsigned int*)l, 16, 0, 0);
}

// ---------- fused fp32->bf16 conversion of x + 4 weights  AND RoPE table tail ----------
// RoPE cos/sin table TRANSPOSED: [32][SEQ]
__global__ void k_conv(const float* __restrict__ x,  const float* __restrict__ wq,
                       const float* __restrict__ wk, const float* __restrict__ wv,
                       const float* __restrict__ wo,
                       unsigned short* __restrict__ xb,  unsigned short* __restrict__ wqb,
                       unsigned short* __restrict__ wkb, unsigned short* __restrict__ wvb,
                       unsigned short* __restrict__ wob,
                       const int* __restrict__ pos,
                       float* __restrict__ ct, float* __restrict__ st)
{
  int i = blockIdx.x * blockDim.x + threadIdx.x;   // float4 index (conversion part)
  const int X4 = MTOT*D_MODEL/4;
  const int W4 = D_MODEL*D_MODEL/4;
  const int CONV_END = X4 + 4*W4;
  if (i < CONV_END) {
    const float* src; unsigned short* dst; int idx;
    if (i < X4) { src = x; dst = xb; idx = i; }
    else {
      int j = i - X4;
      if      (j <   W4) { src = wq; dst = wqb; idx = j; }
      else if (j < 2*W4) { src = wk; dst = wkb; idx = j -   W4; }
      else if (j < 3*W4) { src = wv; dst = wvb; idx = j - 2*W4; }
      else               { src = wo; dst = wob; idx = j - 3*W4; }
    }
    float4 v = ((const float4*)src)[idx];
    ushort4 o;
    o.x = f2bf(v.x); o.y = f2bf(v.y); o.z = f2bf(v.z); o.w = f2bf(v.w);
    ((ushort4*)dst)[idx] = o;
    return;
  }
  // tail: RoPE table, one entry per thread. i2 = j*SEQ + s
  int i2 = i - CONV_END;
  if (i2 >= SEQ*32) return;
  int s = i2 & (SEQ-1), j = i2 >> 12;
  float p = (float)pos[s];
  const float L = 0.2878231366242557f;    // ln(10000)/32
  float freq = __expf(-L * (float)j);     // theta^(-2j/64)
  float a = p * freq;
  ct[i2] = cosf(a);
  st[i2] = sinf(a);
}

// ---------- QKV GEMM (global_load_lds double-buffered) with fused RoPE epilogue ----------
// XCD-aware swizzle (T1): flat grid 1152 = 8 XCDs x 144; XCD owns contiguous m0
// stripes (8 x-values x all 18 (n,z) jobs -> 1.5MB A working set, L2-resident,
// 18x A-row reuse within the XCD). Bijective: u -> rank.
// z=0 -> Q (RoPE + 0.125*log2e scale); z=1 -> K (RoPE); z=2 -> V^T [B,H,64,S]
__global__ __launch_bounds__(256)
void k_gemm_qkv(const unsigned short* __restrict__ X,
                const unsigned short* __restrict__ Wq,
                const unsigned short* __restrict__ Wk,
                const unsigned short* __restrict__ Wv,
                unsigned short* __restrict__ Qp,
                unsigned short* __restrict__ Kp,
                unsigned short* __restrict__ VT,
                const float* __restrict__ ct,
                const float* __restrict__ st)
{
  __shared__ __align__(16) unsigned short As[2][128*32];
  __shared__ __align__(16) unsigned short Bs[2][128*32];
  const int tid = threadIdx.x;
  const int wave = tid >> 6, lane = tid & 63;
  const int lr = lane & 15, lg = lane >> 4;
  const int wr = wave >> 1, wc = wave & 1;
  // XCD swizzle: u%8 = XCD; each XCD gets 144 consecutive ranks (x-major stripes)
  const int u = blockIdx.x;                 // 0..1151
  const int rank = (u & 7) * 144 + (u >> 3);
  const int m0 = (rank / 18) * 128;
  const int w  = rank % 18;
  const int n0 = (w % 6) * 128;
  const int z  = w / 6;
  const unsigned short* B = (z == 0) ? Wq : (z == 1) ? Wk : Wv;
  const int K = 768;

  f32x4 acc[4][4] = {};
  const int srow = tid >> 2, scol = (tid & 3) << 3;
  const unsigned short* ag = X + (size_t)(m0 + srow) * K + scol;
  const unsigned short* bg = B + (size_t)(n0 + srow) * K + scol;

  {
    char* a0 = (char*)As[0] + wave*1024;
    char* a1 = (char*)As[0] + 4096 + wave*1024;
    char* b0 = (char*)Bs[0] + wave*1024;
    char* b1 = (char*)Bs[0] + 4096 + wave*1024;
    gload16(ag, a0);
    gload16(ag + (size_t)64*K, a1);
    gload16(bg, b0);
    gload16(bg + (size_t)64*K, b1);
  }
  int cur = 0;
  for (int k0 = 0; k0 < K; k0 += 32) {
    __syncthreads();                     // buf[cur] ready (vmcnt drained), buf[cur^1] free
    if (k0 + 32 < K) {
      char* a0 = (char*)As[cur^1] + wave*1024;
      char* a1 = (char*)As[cur^1] + 4096 + wave*1024;
      char* b0 = (char*)Bs[cur^1] + wave*1024;
      char* b1 = (char*)Bs[cur^1] + 4096 + wave*1024;
      gload16(ag + k0 + 32, a0);
      gload16(ag + (size_t)64*K + k0 + 32, a1);
      gload16(bg + k0 + 32, b0);
      gload16(bg + (size_t)64*K + k0 + 32, b1);
    }
    short8 af[4], bfr[4];
    #pragma unroll
    for (int i = 0; i < 4; ++i)
      af[i] = *(const short8*)&As[cur][(wr*64 + i*16 + lr)*32 + lg*8];
    #pragma unroll
    for (int j = 0; j < 4; ++j)
      bfr[j] = *(const short8*)&Bs[cur][(wc*64 + j*16 + lr)*32 + lg*8];
    #pragma unroll
    for (int i = 0; i < 4; ++i)
      #pragma unroll
      for (int j = 0; j < 4; ++j)
        acc[i][j] = __builtin_amdgcn_mfma_f32_16x16x32_bf16(af[i], bfr[j], acc[i][j], 0, 0, 0);
    cur ^= 1;
  }

  #pragma unroll
  for (int i = 0; i < 4; ++i)
    #pragma unroll
    for (int j = 0; j < 4; ++j) {
      const int n = n0 + wc*64 + j*16 + lr;      // C col
      const int h = n >> 6, d = n & (HD-1);
      if (z == 2) {
        #pragma unroll
        for (int r = 0; r < 4; ++r) {
          int m = m0 + wr*64 + i*16 + lg*4 + r;
          int bb = m >> 12, s = m & (SEQ-1);
          VT[(((size_t)bb*NHEADS + h)*HD + d)*SEQ + s] = f2bf(acc[i][j][r]);
        }
      } else {
        unsigned short* dst = (z == 0) ? Qp : Kp;
        const int jrow = d >> 1;
        const int mb = m0 + wr*64 + i*16 + lg*4;
        const int bb = mb >> 12;
        const int sbase = mb & (SEQ-1);
        f32x4 cs4 = *(const f32x4*)(ct + (size_t)jrow*SEQ + sbase);
        f32x4 sn4 = *(const f32x4*)(st + (size_t)jrow*SEQ + sbase);
        #pragma unroll
        for (int r = 0; r < 4; ++r) {
          float vv = acc[i][j][r];
          float pp = __shfl_xor(vv, 1);          // paired element (col n^1, lane^1)
          float res = (d & 1) ? (vv*cs4[r] + pp*sn4[r]) : (vv*cs4[r] - pp*sn4[r]);
          if (z == 0) res *= 0.18033688011112043f;   // 1/8 * log2(e)
          dst[(((size_t)bb*NHEADS + h)*SEQ + (sbase + r))*HD + d] = f2bf(res);
        }
      }
    }
}

// ---------- WO GEMM (128x128, global_load_lds double-buffered): AO @ WO^T -> fp32 ----------
// XCD-aware swizzle: 384 = 8 x 48; XCD owns contiguous m0 stripes (6x A reuse).
__global__ __launch_bounds__(256)
void k_gemm_wo(const unsigned short* __restrict__ X,
               const unsigned short* __restrict__ W,
               float* __restrict__ out)
{
  __shared__ __align__(16) unsigned short As[2][128*32];
  __shared__ __align__(16) unsigned short Bs[2][128*32];
  const int tid = threadIdx.x;
  const int wave = tid >> 6, lane = tid & 63;
  const int lr = lane & 15, lg = lane >> 4;
  const int wr = wave >> 1, wc = wave & 1;
  const int u = blockIdx.x;                 // 0..383
  const int rank = (u & 7) * 48 + (u >> 3);
  const int m0 = (rank / 6) * 128;
  const int n0 = (rank % 6) * 128;
  const int K = 768;

  f32x4 acc[4][4] = {};
  const int srow = tid >> 2, scol = (tid & 3) << 3;
  const unsigned short* ag = X + (size_t)(m0 + srow) * K + scol;
  const unsigned short* bg = W + (size_t)(n0 + srow) * K + scol;

  {
    char* a0 = (char*)As[0] + wave*1024;
    char* a1 = (char*)As[0] + 4096 + wave*1024;
    char* b0 = (char*)Bs[0] + wave*1024;
    char* b1 = (char*)Bs[0] + 4096 + wave*1024;
    gload16(ag, a0);
    gload16(ag + (size_t)64*K, a1);
    gload16(bg, b0);
    gload16(bg + (size_t)64*K, b1);
  }
  int cur = 0;
  for (int k0 = 0; k0 < K; k0 += 32) {
    __syncthreads();
    if (k0 + 32 < K) {
      char* a0 = (char*)As[cur^1] + wave*1024;
      char* a1 = (char*)As[cur^1] + 4096 + wave*1024;
      char* b0 = (char*)Bs[cur^1] + wave*1024;
      char* b1 = (char*)Bs[cur^1] + 4096 + wave*1024;
      gload16(ag + k0 + 32, a0);
      gload16(ag + (size_t)64*K + k0 + 32, a1);
      gload16(bg + k0 + 32, b0);
      gload16(bg + (size_t)64*K + k0 + 32, b1);
    }
    short8 af[4], bfr[4];
    #pragma unroll
    for (int i = 0; i < 4; ++i)
      af[i] = *(const short8*)&As[cur][(wr*64 + i*16 + lr)*32 + lg*8];
    #pragma unroll
    for (int j = 0; j < 4; ++j)
      bfr[j] = *(const short8*)&Bs[cur][(wc*64 + j*16 + lr)*32 + lg*8];
    #pragma unroll
    for (int i = 0; i < 4; ++i)
      #pragma unroll
      for (int j = 0; j < 4; ++j)
        acc[i][j] = __builtin_amdgcn_mfma_f32_16x16x32_bf16(af[i], bfr[j], acc[i][j], 0, 0, 0);
    cur ^= 1;
  }

  #pragma unroll
  for (int i = 0; i < 4; ++i)
    #pragma unroll
    for (int j = 0; j < 4; ++j)
      #pragma unroll
      for (int r = 0; r < 4; ++r) {
        int m = m0 + wr*64 + i*16 + lg*4 + r;
        int n = n0 + wc*64 + j*16 + lr;
        out[(size_t)m*D_MODEL + n] = acc[i][j][r];
      }
}

// ---------- causal flash attention v9 (best measured: 89.4 us) ----------
// 2-buffer gload_lds staging (pre-swizzled source, linear dest), static-m
// softmax (P = exp2(S) directly), l via ones-row MFMA, rank remap for CU
// balance. R13 counted-vmcnt: null. R14 chunk-blocks: null. R15 zero-LDS:
// regression (latency-bound). This configuration is the local optimum.
__global__ __launch_bounds__(256, 3)
void k_attn(const unsigned short* __restrict__ Qp,
            const unsigned short* __restrict__ Kp,
            const unsigned short* __restrict__ VT,
            unsigned short* __restrict__ AO)
{
  __shared__ __align__(16) unsigned short Ks[2][64*64];
  __shared__ __align__(16) unsigned short Vs[2][64*64];

  const int tid = threadIdx.x;
  const int wave = tid >> 6, lane = tid & 63;
  const int qcol = lane & 31, hi = lane >> 5;

  // ---- balanced job mapping (CU g gets ranks {g, 767-g, 256+g})
  const int u = blockIdx.x;                 // 0..767
  const int kk = u >> 8, g = u & 255;
  const int rank = (kk == 0) ? g : (kk == 1) ? (767 - g) : (256 + g);
  const int cpair = rank / 24;              // 0..31; rank 0 = longest job
  const int bh = rank - cpair * 24;

  const int b = bh / NHEADS, h = bh % NHEADS;
  const int chunk = (wave < 2) ? cpair : 63 - cpair;
  const int qw = chunk * 64 + (wave & 1) * 32;     // this wave's 32 q-rows
  const int nt = 64 - cpair;                       // staged k-tiles
  const int myNt = qw / 64 + 1;                    // tiles this wave computes

  const unsigned short* Qh = Qp + (size_t)bh * SEQ * HD;
  const unsigned short* Kh = Kp + (size_t)bh * SEQ * HD;
  const unsigned short* Vh = VT + (size_t)bh * HD * SEQ;

  // Q fragment (B-operand): col=q=qcol, k-slot = hi*8+i per 16-d slice
  short8 qf[4];
  #pragma unroll
  for (int ds = 0; ds < 4; ++ds)
    qf[ds] = *(const short8*)(Qh + (size_t)(qw + qcol)*HD + ds*16 + hi*8);

  // all-ones bf16 A-fragment for the l-row MFMA
  short8 onesf;
  #pragma unroll
  for (int i = 0; i < 8; ++i) onesf[i] = (short)0x3F80;

  f32x16 o[2] = {};          // O^T accum: col=q=qcol
  f32x16 lacc = {};          // l accumulator (all rows equal = sum_k P[k][q])

  // staging map: row = tid>>3, seg = tid&7; lds byte = tid*16 (linear dest).
  const int g_row = tid >> 3;
  const int sgp = ((tid & 7) ^ (g_row & 7)) * 8;   // pre-swizzled source col

  { // prologue: stage tile 0 into buf 0
    gload16(Kh + (size_t)g_row*HD + sgp,          (char*)Ks[0] + wave*1024);
    gload16(Kh + (size_t)(g_row + 32)*HD + sgp,   (char*)Ks[0] + 4096 + wave*1024);
    gload16(Vh + (size_t)g_row*SEQ + sgp,         (char*)Vs[0] + wave*1024);
    gload16(Vh + (size_t)(g_row + 32)*SEQ + sgp,  (char*)Vs[0] + 4096 + wave*1024);
  }
  __syncthreads();

  int cur = 0;
  for (int kt = 0; kt < nt; ++kt) {
    // issue next tile's async loads (land by this iteration's barrier drain)
    if (kt + 1 < nt) {
      const size_t kb = (size_t)(kt + 1) * 64;
      gload16(Kh + (kb + g_row)*HD + sgp,            (char*)Ks[cur^1] + wave*1024);
      gload16(Kh + (kb + g_row + 32)*HD + sgp,       (char*)Ks[cur^1] + 4096 + wave*1024);
      gload16(Vh + (size_t)g_row*SEQ + kb + sgp,     (char*)Vs[cur^1] + wave*1024);
      gload16(Vh + (size_t)(g_row + 32)*SEQ + kb + sgp, (char*)Vs[cur^1] + 4096 + wave*1024);
    }
    if (kt < myNt) {
      const char* Kb = (const char*)Ks[cur];
      const char* Vb = (const char*)Vs[cur];
      // ---- QK^T (swapped): S^T[key][q], log2 domain (Q pre-scaled by 0.125*log2e)
      f32x16 c[2];
      __builtin_amdgcn_s_setprio(1);
      #pragma unroll
      for (int kc = 0; kc < 2; ++kc) {
        f32x16 acc = {};
        #pragma unroll
        for (int ds = 0; ds < 4; ++ds) {
          const int row = kc*32 + qcol;   // key row
          short8 kf = *(const short8*)(Kb + row*128 + ((ds*32 + hi*16) ^ ((row & 7) << 4)));
          acc = __builtin_amdgcn_mfma_f32_32x32x16_bf16(kf, qf[ds], acc, 0, 0, 0);
        }
        c[kc] = acc;
      }
      __builtin_amdgcn_s_setprio(0);
      // ---- causal mask (diagonal tile only)
      if (kt == myNt - 1) {
        const int q = qw + qcol;
        #pragma unroll
        for (int kc = 0; kc < 2; ++kc)
          #pragma unroll
          for (int r = 0; r < 16; ++r) {
            int key = kt*64 + kc*32 + (r & 3) + 8*(r >> 2) + 4*hi;
            if (key > q) c[kc][r] = -1e30f;
          }
      }
      // ---- P = exp2(S) directly (static m = 0)
      #pragma unroll
      for (int kc = 0; kc < 2; ++kc)
        #pragma unroll
        for (int r = 0; r < 16; ++r)
          c[kc][r] = exp2fast(c[kc][r]);
      // ---- pack P to bf16 pairs: U[g][p] holds keys 8g+4hi+2p, +1
      unsigned U[8][2];
      #pragma unroll
      for (int g2 = 0; g2 < 8; ++g2) {
        const int fc = g2 >> 2, gq = g2 & 3;
        U[g2][0] = cvtpk_bf16(c[fc][4*gq + 0], c[fc][4*gq + 1]);
        U[g2][1] = cvtpk_bf16(c[fc][4*gq + 2], c[fc][4*gq + 3]);
      }
      // ---- PV (swapped): O^T += V-frag x P-frag; l += ones x P-frag
      #pragma unroll
      for (int ks = 0; ks < 4; ++ks) {
        unsigned j0 = U[2*ks][0], j2 = U[2*ks+1][0];
        perm32swap(j0, j2);
        unsigned j1 = U[2*ks][1], j3 = U[2*ks+1][1];
        perm32swap(j1, j3);
        union { unsigned u[4]; short8 s; } pf;
        pf.u[0] = j0; pf.u[1] = j1; pf.u[2] = j2; pf.u[3] = j3;
        __builtin_amdgcn_s_setprio(1);
        #pragma unroll
        for (int dc = 0; dc < 2; ++dc) {
          const int row = dc*32 + qcol;
          short8 vf = *(const short8*)(Vb + row*128 + ((ks*32 + hi*16) ^ ((row & 7) << 4)));
          o[dc] = __builtin_amdgcn_mfma_f32_32x32x16_bf16(vf, pf.s, o[dc], 0, 0, 0);
        }
        lacc = __builtin_amdgcn_mfma_f32_32x32x16_bf16(onesf, pf.s, lacc, 0, 0, 0);
        __builtin_amdgcn_s_setprio(0);
      }
    }
    __syncthreads();      // drains gloads (compiler vmcnt) + sync buffer swap
    cur ^= 1;
  }

  // ---- epilogue: l = lacc[0] (all rows equal); O^T / l; packed 8B stores
  const float inv = 1.0f / lacc[0];
  const size_t rowbase = ((size_t)b*SEQ + qw + qcol) * D_MODEL + h*HD;
  #pragma unroll
  for (int dc = 0; dc < 2; ++dc)
    #pragma unroll
    for (int g2 = 0; g2 < 4; ++g2) {
      ushort4 pk;
      pk.x = f2bf(o[dc][4*g2 + 0] * inv);
      pk.y = f2bf(o[dc][4*g2 + 1] * inv);
      pk.z = f2bf(o[dc][4*g2 + 2] * inv);
      pk.w = f2bf(o[dc][4*g2 + 3] * inv);
      const int d0 = dc*32 + 8*g2 + 4*hi;
      *(ushort4*)(AO + rowbase + d0) = pk;
    }
}

extern "C" void kernel_launch(void* const* d_in, const int* in_sizes, int n_in,
                              void* d_out, int out_size, void* d_ws, size_t ws_size,
                              hipStream_t stream)
{
  const float* x  = (const float*)d_in[0];
  const int* posi = (const int*)d_in[1];
  const float* wq = (const float*)d_in[2];
  const float* wk = (const float*)d_in[3];
  const float* wv = (const float*)d_in[4];
  const float* wo = (const float*)d_in[5];
  float* out = (float*)d_out;

  char* ws = (char*)d_ws;
  size_t off = 0;
  auto alloc = [&](size_t bytes) {
    char* p = ws + off;
    off += (bytes + 255) & ~(size_t)255;
    return p;
  };
  unsigned short* xb  = (unsigned short*)alloc((size_t)MTOT*D_MODEL*2);
  unsigned short* wqb = (unsigned short*)alloc((size_t)D_MODEL*D_MODEL*2);
  unsigned short* wkb = (unsigned short*)alloc((size_t)D_MODEL*D_MODEL*2);
  unsigned short* wvb = (unsigned short*)alloc((size_t)D_MODEL*D_MODEL*2);
  unsigned short* wob = (unsigned short*)alloc((size_t)D_MODEL*D_MODEL*2);
  unsigned short* Qb  = (unsigned short*)alloc((size_t)BHN*SEQ*HD*2);
  unsigned short* Kb  = (unsigned short*)alloc((size_t)BHN*SEQ*HD*2);
  unsigned short* VTb = (unsigned short*)alloc((size_t)BHN*HD*SEQ*2);
  unsigned short* AOb = (unsigned short*)alloc((size_t)MTOT*D_MODEL*2);
  float* ct = (float*)alloc((size_t)SEQ*32*4);
  float* st = (float*)alloc((size_t)SEQ*32*4);

  const int total = MTOT*D_MODEL/4 + 4*(D_MODEL*D_MODEL/4) + SEQ*32;
  k_conv<<<(total + 255)/256, 256, 0, stream>>>(x, wq, wk, wv, wo,
                                                xb, wqb, wkb, wvb, wob,
                                                posi, ct, st);

  k_gemm_qkv<<<dim3(1152), 256, 0, stream>>>(xb, wqb, wkb, wvb, Qb, Kb, VTb, ct, st);
  k_attn<<<dim3(768), 256, 0, stream>>>(Qb, Kb, VTb, AOb);
  k_gemm_wo<<<dim3(384), 256, 0, stream>>>(AOb, wob, out);
}

// Round 20
// 166.057 us; speedup vs baseline: 1.0168x; 1.0168x over previous
//
#include <hip/hip_runtime.h>
#include <hip/hip_bf16.h>
#include <stdint.h>

#define D_MODEL 768
#define NHEADS 12
#define HD 64
#define SEQ 4096
#define BATCH 2
#define MTOT (BATCH*SEQ)        // 8192
#define BHN (BATCH*NHEADS)      // 24

typedef __attribute__((ext_vector_type(8))) short short8;
typedef __attribute__((ext_vector_type(4))) float f32x4;
typedef __attribute__((ext_vector_type(16))) float f32x16;
typedef __attribute__((ext_vector_type(4))) int i32x4;

__device__ inline unsigned short f2bf(float f) {
  union { float f; unsigned u; } v; v.f = f;
  unsigned r = (v.u + 0x7FFFu + ((v.u >> 16) & 1u)) >> 16;
  return (unsigned short)r;
}
__device__ inline unsigned cvtpk_bf16(float lo, float hi) {
  unsigned r;
  asm("v_cvt_pk_bf16_f32 %0, %1, %2" : "=v"(r) : "v"(lo), "v"(hi));
  return r;
}
__device__ inline void perm32swap(unsigned &a, unsigned &b) {
  asm("v_permlane32_swap_b32 %0, %1" : "+v"(a), "+v"(b));
}
__device__ inline float exp2fast(float x) {   // v_exp_f32: D = 2^S0
  float r;
  asm("v_exp_f32 %0, %1" : "=v"(r) : "v"(x));
  return r;
}
// async global->LDS, 16B per lane. lds dest = wave-uniform base + lane*16.
__device__ inline void gload16(const void* g, void* l) {
  __builtin_amdgcn_global_load_lds(
      (const __attribute__((address_space(1))) unsigned int*)g,
      (__attribute__((address_space(3))) unsigned int*)l, 16, 0, 0);
}

// ---------- fused fp32->bf16 conversion of x + 4 weights  AND RoPE table tail ----------
// RoPE cos/sin table TRANSPOSED: [32][SEQ]
__global__ void k_conv(const float* __restrict__ x,  const float* __restrict__ wq,
                       const float* __restrict__ wk, const float* __restrict__ wv,
                       const float* __restrict__ wo,
                       unsigned short* __restrict__ xb,  unsigned short* __restrict__ wqb,
                       unsigned short* __restrict__ wkb, unsigned short* __restrict__ wvb,
                       unsigned short* __restrict__ wob,
                       const int* __restrict__ pos,
                       float* __restrict__ ct, float* __restrict__ st)
{
  int i = blockIdx.x * blockDim.x + threadIdx.x;   // float4 index (conversion part)
  const int X4 = MTOT*D_MODEL/4;
  const int W4 = D_MODEL*D_MODEL/4;
  const int CONV_END = X4 + 4*W4;
  if (i < CONV_END) {
    const float* src; unsigned short* dst; int idx;
    if (i < X4) { src = x; dst = xb; idx = i; }
    else {
      int j = i - X4;
      if      (j <   W4) { src = wq; dst = wqb; idx = j; }
      else if (j < 2*W4) { src = wk; dst = wkb; idx = j -   W4; }
      else if (j < 3*W4) { src = wv; dst = wvb; idx = j - 2*W4; }
      else               { src = wo; dst = wob; idx = j - 3*W4; }
    }
    float4 v = ((const float4*)src)[idx];
    ushort4 o;
    o.x = f2bf(v.x); o.y = f2bf(v.y); o.z = f2bf(v.z); o.w = f2bf(v.w);
    ((ushort4*)dst)[idx] = o;
    return;
  }
  // tail: RoPE table, one entry per thread. i2 = j*SEQ + s
  int i2 = i - CONV_END;
  if (i2 >= SEQ*32) return;
  int s = i2 & (SEQ-1), j = i2 >> 12;
  float p = (float)pos[s];
  const float L = 0.2878231366242557f;    // ln(10000)/32
  float freq = __expf(-L * (float)j);     // theta^(-2j/64)
  float a = p * freq;
  ct[i2] = cosf(a);
  st[i2] = sinf(a);
}

// ---------- QKV GEMM (global_load_lds double-buffered) with fused RoPE epilogue ----------
// z=0 -> Q [B,H,S,64] (RoPE + 0.125*log2e scale); z=1 -> K (RoPE); z=2 -> V^T [B,H,64,S]
__global__ __launch_bounds__(256)
void k_gemm_qkv(const unsigned short* __restrict__ X,
                const unsigned short* __restrict__ Wq,
                const unsigned short* __restrict__ Wk,
                const unsigned short* __restrict__ Wv,
                unsigned short* __restrict__ Qp,
                unsigned short* __restrict__ Kp,
                unsigned short* __restrict__ VT,
                const float* __restrict__ ct,
                const float* __restrict__ st)
{
  __shared__ __align__(16) unsigned short As[2][128*32];
  __shared__ __align__(16) unsigned short Bs[2][128*32];
  const int tid = threadIdx.x;
  const int wave = tid >> 6, lane = tid & 63;
  const int lr = lane & 15, lg = lane >> 4;
  const int wr = wave >> 1, wc = wave & 1;
  const int m0 = blockIdx.x * 128;
  const int n0 = blockIdx.y * 128;
  const int z  = blockIdx.z;
  const unsigned short* B = (z == 0) ? Wq : (z == 1) ? Wk : Wv;
  const int K = 768;

  f32x4 acc[4][4] = {};
  const int srow = tid >> 2, scol = (tid & 3) << 3;
  const unsigned short* ag = X + (size_t)(m0 + srow) * K + scol;
  const unsigned short* bg = B + (size_t)(n0 + srow) * K + scol;

  {
    char* a0 = (char*)As[0] + wave*1024;
    char* a1 = (char*)As[0] + 4096 + wave*1024;
    char* b0 = (char*)Bs[0] + wave*1024;
    char* b1 = (char*)Bs[0] + 4096 + wave*1024;
    gload16(ag, a0);
    gload16(ag + (size_t)64*K, a1);
    gload16(bg, b0);
    gload16(bg + (size_t)64*K, b1);
  }
  int cur = 0;
  for (int k0 = 0; k0 < K; k0 += 32) {
    __syncthreads();                     // buf[cur] ready (vmcnt drained), buf[cur^1] free
    if (k0 + 32 < K) {
      char* a0 = (char*)As[cur^1] + wave*1024;
      char* a1 = (char*)As[cur^1] + 4096 + wave*1024;
      char* b0 = (char*)Bs[cur^1] + wave*1024;
      char* b1 = (char*)Bs[cur^1] + 4096 + wave*1024;
      gload16(ag + k0 + 32, a0);
      gload16(ag + (size_t)64*K + k0 + 32, a1);
      gload16(bg + k0 + 32, b0);
      gload16(bg + (size_t)64*K + k0 + 32, b1);
    }
    short8 af[4], bfr[4];
    #pragma unroll
    for (int i = 0; i < 4; ++i)
      af[i] = *(const short8*)&As[cur][(wr*64 + i*16 + lr)*32 + lg*8];
    #pragma unroll
    for (int j = 0; j < 4; ++j)
      bfr[j] = *(const short8*)&Bs[cur][(wc*64 + j*16 + lr)*32 + lg*8];
    #pragma unroll
    for (int i = 0; i < 4; ++i)
      #pragma unroll
      for (int j = 0; j < 4; ++j)
        acc[i][j] = __builtin_amdgcn_mfma_f32_16x16x32_bf16(af[i], bfr[j], acc[i][j], 0, 0, 0);
    cur ^= 1;
  }

  #pragma unroll
  for (int i = 0; i < 4; ++i)
    #pragma unroll
    for (int j = 0; j < 4; ++j) {
      const int n = n0 + wc*64 + j*16 + lr;      // C col
      const int h = n >> 6, d = n & (HD-1);
      if (z == 2) {
        #pragma unroll
        for (int r = 0; r < 4; ++r) {
          int m = m0 + wr*64 + i*16 + lg*4 + r;
          int bb = m >> 12, s = m & (SEQ-1);
          VT[(((size_t)bb*NHEADS + h)*HD + d)*SEQ + s] = f2bf(acc[i][j][r]);
        }
      } else {
        unsigned short* dst = (z == 0) ? Qp : Kp;
        const int jrow = d >> 1;
        const int mb = m0 + wr*64 + i*16 + lg*4;
        const int bb = mb >> 12;
        const int sbase = mb & (SEQ-1);
        f32x4 cs4 = *(const f32x4*)(ct + (size_t)jrow*SEQ + sbase);
        f32x4 sn4 = *(const f32x4*)(st + (size_t)jrow*SEQ + sbase);
        #pragma unroll
        for (int r = 0; r < 4; ++r) {
          float vv = acc[i][j][r];
          float pp = __shfl_xor(vv, 1);          // paired element (col n^1, lane^1)
          float res = (d & 1) ? (vv*cs4[r] + pp*sn4[r]) : (vv*cs4[r] - pp*sn4[r]);
          if (z == 0) res *= 0.18033688011112043f;   // 1/8 * log2(e)
          dst[(((size_t)bb*NHEADS + h)*SEQ + (sbase + r))*HD + d] = f2bf(res);
        }
      }
    }
}

// ---------- WO GEMM (128x128, global_load_lds double-buffered): AO @ WO^T -> fp32 ----------
__global__ __launch_bounds__(256)
void k_gemm_wo(const unsigned short* __restrict__ X,
               const unsigned short* __restrict__ W,
               float* __restrict__ out)
{
  __shared__ __align__(16) unsigned short As[2][128*32];
  __shared__ __align__(16) unsigned short Bs[2][128*32];
  const int tid = threadIdx.x;
  const int wave = tid >> 6, lane = tid & 63;
  const int lr = lane & 15, lg = lane >> 4;
  const int wr = wave >> 1, wc = wave & 1;
  const int m0 = blockIdx.x * 128;
  const int n0 = blockIdx.y * 128;
  const int K = 768;

  f32x4 acc[4][4] = {};
  const int srow = tid >> 2, scol = (tid & 3) << 3;
  const unsigned short* ag = X + (size_t)(m0 + srow) * K + scol;
  const unsigned short* bg = W + (size_t)(n0 + srow) * K + scol;

  {
    char* a0 = (char*)As[0] + wave*1024;
    char* a1 = (char*)As[0] + 4096 + wave*1024;
    char* b0 = (char*)Bs[0] + wave*1024;
    char* b1 = (char*)Bs[0] + 4096 + wave*1024;
    gload16(ag, a0);
    gload16(ag + (size_t)64*K, a1);
    gload16(bg, b0);
    gload16(bg + (size_t)64*K, b1);
  }
  int cur = 0;
  for (int k0 = 0; k0 < K; k0 += 32) {
    __syncthreads();
    if (k0 + 32 < K) {
      char* a0 = (char*)As[cur^1] + wave*1024;
      char* a1 = (char*)As[cur^1] + 4096 + wave*1024;
      char* b0 = (char*)Bs[cur^1] + wave*1024;
      char* b1 = (char*)Bs[cur^1] + 4096 + wave*1024;
      gload16(ag + k0 + 32, a0);
      gload16(ag + (size_t)64*K + k0 + 32, a1);
      gload16(bg + k0 + 32, b0);
      gload16(bg + (size_t)64*K + k0 + 32, b1);
    }
    short8 af[4], bfr[4];
    #pragma unroll
    for (int i = 0; i < 4; ++i)
      af[i] = *(const short8*)&As[cur][(wr*64 + i*16 + lr)*32 + lg*8];
    #pragma unroll
    for (int j = 0; j < 4; ++j)
      bfr[j] = *(const short8*)&Bs[cur][(wc*64 + j*16 + lr)*32 + lg*8];
    #pragma unroll
    for (int i = 0; i < 4; ++i)
      #pragma unroll
      for (int j = 0; j < 4; ++j)
        acc[i][j] = __builtin_amdgcn_mfma_f32_16x16x32_bf16(af[i], bfr[j], acc[i][j], 0, 0, 0);
    cur ^= 1;
  }

  #pragma unroll
  for (int i = 0; i < 4; ++i)
    #pragma unroll
    for (int j = 0; j < 4; ++j)
      #pragma unroll
      for (int r = 0; r < 4; ++r) {
        int m = m0 + wr*64 + i*16 + lg*4 + r;
        int n = n0 + wc*64 + j*16 + lr;
        out[(size_t)m*D_MODEL + n] = acc[i][j][r];
      }
}

// ---------- causal flash attention v9 (best measured: 89.4 us) ----------
// 2-buffer gload_lds staging (pre-swizzled source, linear dest), static-m
// softmax (P = exp2(S) directly), l via ones-row MFMA, rank remap for CU
// balance. R13 counted-vmcnt: null. R14 chunk-blocks: null. R15 zero-LDS:
// regression (latency-bound). This configuration is the local optimum.
__global__ __launch_bounds__(256, 3)
void k_attn(const unsigned short* __restrict__ Qp,
            const unsigned short* __restrict__ Kp,
            const unsigned short* __restrict__ VT,
            unsigned short* __restrict__ AO)
{
  __shared__ __align__(16) unsigned short Ks[2][64*64];
  __shared__ __align__(16) unsigned short Vs[2][64*64];

  const int tid = threadIdx.x;
  const int wave = tid >> 6, lane = tid & 63;
  const int qcol = lane & 31, hi = lane >> 5;

  // ---- balanced job mapping (CU g gets ranks {g, 767-g, 256+g})
  const int u = blockIdx.x;                 // 0..767
  const int kk = u >> 8, g = u & 255;
  const int rank = (kk == 0) ? g : (kk == 1) ? (767 - g) : (256 + g);
  const int cpair = rank / 24;              // 0..31; rank 0 = longest job
  const int bh = rank - cpair * 24;

  const int b = bh / NHEADS, h = bh % NHEADS;
  const int chunk = (wave < 2) ? cpair : 63 - cpair;
  const int qw = chunk * 64 + (wave & 1) * 32;     // this wave's 32 q-rows
  const int nt = 64 - cpair;                       // staged k-tiles
  const int myNt = qw / 64 + 1;                    // tiles this wave computes

  const unsigned short* Qh = Qp + (size_t)bh * SEQ * HD;
  const unsigned short* Kh = Kp + (size_t)bh * SEQ * HD;
  const unsigned short* Vh = VT + (size_t)bh * HD * SEQ;

  // Q fragment (B-operand): col=q=qcol, k-slot = hi*8+i per 16-d slice
  short8 qf[4];
  #pragma unroll
  for (int ds = 0; ds < 4; ++ds)
    qf[ds] = *(const short8*)(Qh + (size_t)(qw + qcol)*HD + ds*16 + hi*8);

  // all-ones bf16 A-fragment for the l-row MFMA
  short8 onesf;
  #pragma unroll
  for (int i = 0; i < 8; ++i) onesf[i] = (short)0x3F80;

  f32x16 o[2] = {};          // O^T accum: col=q=qcol
  f32x16 lacc = {};          // l accumulator (all rows equal = sum_k P[k][q])

  // staging map: row = tid>>3, seg = tid&7; lds byte = tid*16 (linear dest).
  const int g_row = tid >> 3;
  const int sgp = ((tid & 7) ^ (g_row & 7)) * 8;   // pre-swizzled source col

  { // prologue: stage tile 0 into buf 0
    gload16(Kh + (size_t)g_row*HD + sgp,          (char*)Ks[0] + wave*1024);
    gload16(Kh + (size_t)(g_row + 32)*HD + sgp,   (char*)Ks[0] + 4096 + wave*1024);
    gload16(Vh + (size_t)g_row*SEQ + sgp,         (char*)Vs[0] + wave*1024);
    gload16(Vh + (size_t)(g_row + 32)*SEQ + sgp,  (char*)Vs[0] + 4096 + wave*1024);
  }
  __syncthreads();

  int cur = 0;
  for (int kt = 0; kt < nt; ++kt) {
    // issue next tile's async loads (land by this iteration's barrier drain)
    if (kt + 1 < nt) {
      const size_t kb = (size_t)(kt + 1) * 64;
      gload16(Kh + (kb + g_row)*HD + sgp,            (char*)Ks[cur^1] + wave*1024);
      gload16(Kh + (kb + g_row + 32)*HD + sgp,       (char*)Ks[cur^1] + 4096 + wave*1024);
      gload16(Vh + (size_t)g_row*SEQ + kb + sgp,     (char*)Vs[cur^1] + wave*1024);
      gload16(Vh + (size_t)(g_row + 32)*SEQ + kb + sgp, (char*)Vs[cur^1] + 4096 + wave*1024);
    }
    if (kt < myNt) {
      const char* Kb = (const char*)Ks[cur];
      const char* Vb = (const char*)Vs[cur];
      // ---- QK^T (swapped): S^T[key][q], log2 domain (Q pre-scaled by 0.125*log2e)
      f32x16 c[2];
      __builtin_amdgcn_s_setprio(1);
      #pragma unroll
      for (int kc = 0; kc < 2; ++kc) {
        f32x16 acc = {};
        #pragma unroll
        for (int ds = 0; ds < 4; ++ds) {
          const int row = kc*32 + qcol;   // key row
          short8 kf = *(const short8*)(Kb + row*128 + ((ds*32 + hi*16) ^ ((row & 7) << 4)));
          acc = __builtin_amdgcn_mfma_f32_32x32x16_bf16(kf, qf[ds], acc, 0, 0, 0);
        }
        c[kc] = acc;
      }
      __builtin_amdgcn_s_setprio(0);
      // ---- causal mask (diagonal tile only)
      if (kt == myNt - 1) {
        const int q = qw + qcol;
        #pragma unroll
        for (int kc = 0; kc < 2; ++kc)
          #pragma unroll
          for (int r = 0; r < 16; ++r) {
            int key = kt*64 + kc*32 + (r & 3) + 8*(r >> 2) + 4*hi;
            if (key > q) c[kc][r] = -1e30f;
          }
      }
      // ---- P = exp2(S) directly (static m = 0)
      #pragma unroll
      for (int kc = 0; kc < 2; ++kc)
        #pragma unroll
        for (int r = 0; r < 16; ++r)
          c[kc][r] = exp2fast(c[kc][r]);
      // ---- pack P to bf16 pairs: U[g][p] holds keys 8g+4hi+2p, +1
      unsigned U[8][2];
      #pragma unroll
      for (int g2 = 0; g2 < 8; ++g2) {
        const int fc = g2 >> 2, gq = g2 & 3;
        U[g2][0] = cvtpk_bf16(c[fc][4*gq + 0], c[fc][4*gq + 1]);
        U[g2][1] = cvtpk_bf16(c[fc][4*gq + 2], c[fc][4*gq + 3]);
      }
      // ---- PV (swapped): O^T += V-frag x P-frag; l += ones x P-frag
      #pragma unroll
      for (int ks = 0; ks < 4; ++ks) {
        unsigned j0 = U[2*ks][0], j2 = U[2*ks+1][0];
        perm32swap(j0, j2);
        unsigned j1 = U[2*ks][1], j3 = U[2*ks+1][1];
        perm32swap(j1, j3);
        union { unsigned u[4]; short8 s; } pf;
        pf.u[0] = j0; pf.u[1] = j1; pf.u[2] = j2; pf.u[3] = j3;
        __builtin_amdgcn_s_setprio(1);
        #pragma unroll
        for (int dc = 0; dc < 2; ++dc) {
          const int row = dc*32 + qcol;
          short8 vf = *(const short8*)(Vb + row*128 + ((ks*32 + hi*16) ^ ((row & 7) << 4)));
          o[dc] = __builtin_amdgcn_mfma_f32_32x32x16_bf16(vf, pf.s, o[dc], 0, 0, 0);
        }
        lacc = __builtin_amdgcn_mfma_f32_32x32x16_bf16(onesf, pf.s, lacc, 0, 0, 0);
        __builtin_amdgcn_s_setprio(0);
      }
    }
    __syncthreads();      // drains gloads (compiler vmcnt) + sync buffer swap
    cur ^= 1;
  }

  // ---- epilogue: l = lacc[0] (all rows equal); O^T / l; packed 8B stores
  const float inv = 1.0f / lacc[0];
  const size_t rowbase = ((size_t)b*SEQ + qw + qcol) * D_MODEL + h*HD;
  #pragma unroll
  for (int dc = 0; dc < 2; ++dc)
    #pragma unroll
    for (int g2 = 0; g2 < 4; ++g2) {
      ushort4 pk;
      pk.x = f2bf(o[dc][4*g2 + 0] * inv);
      pk.y = f2bf(o[dc][4*g2 + 1] * inv);
      pk.z = f2bf(o[dc][4*g2 + 2] * inv);
      pk.w = f2bf(o[dc][4*g2 + 3] * inv);
      const int d0 = dc*32 + 8*g2 + 4*hi;
      *(ushort4*)(AO + rowbase + d0) = pk;
    }
}

extern "C" void kernel_launch(void* const* d_in, const int* in_sizes, int n_in,
                              void* d_out, int out_size, void* d_ws, size_t ws_size,
                              hipStream_t stream)
{
  const float* x  = (const float*)d_in[0];
  const int* posi = (const int*)d_in[1];
  const float* wq = (const float*)d_in[2];
  const float* wk = (const float*)d_in[3];
  const float* wv = (const float*)d_in[4];
  const float* wo = (const float*)d_in[5];
  float* out = (float*)d_out;

  char* ws = (char*)d_ws;
  size_t off = 0;
  auto alloc = [&](size_t bytes) {
    char* p = ws + off;
    off += (bytes + 255) & ~(size_t)255;
    return p;
  };
  unsigned short* xb  = (unsigned short*)alloc((size_t)MTOT*D_MODEL*2);
  unsigned short* wqb = (unsigned short*)alloc((size_t)D_MODEL*D_MODEL*2);
  unsigned short* wkb = (unsigned short*)alloc((size_t)D_MODEL*D_MODEL*2);
  unsigned short* wvb = (unsigned short*)alloc((size_t)D_MODEL*D_MODEL*2);
  unsigned short* wob = (unsigned short*)alloc((size_t)D_MODEL*D_MODEL*2);
  unsigned short* Qb  = (unsigned short*)alloc((size_t)BHN*SEQ*HD*2);
  unsigned short* Kb  = (unsigned short*)alloc((size_t)BHN*SEQ*HD*2);
  unsigned short* VTb = (unsigned short*)alloc((size_t)BHN*HD*SEQ*2);
  unsigned short* AOb = (unsigned short*)alloc((size_t)MTOT*D_MODEL*2);
  float* ct = (float*)alloc((size_t)SEQ*32*4);
  float* st = (float*)alloc((size_t)SEQ*32*4);

  const int total = MTOT*D_MODEL/4 + 4*(D_MODEL*D_MODEL/4) + SEQ*32;
  k_conv<<<(total + 255)/256, 256, 0, stream>>>(x, wq, wk, wv, wo,
                                                xb, wqb, wkb, wvb, wob,
                                                posi, ct, st);

  k_gemm_qkv<<<dim3(MTOT/128, D_MODEL/128, 3), 256, 0, stream>>>(xb, wqb, wkb, wvb, Qb, Kb, VTb, ct, st);
  k_attn<<<dim3(768), 256, 0, stream>>>(Qb, Kb, VTb, AOb);
  k_gemm_wo<<<dim3(MTOT/128, D_MODEL/128), 256, 0, stream>>>(AOb, wob, out);
}